// Round 1
// baseline (588.009 us; speedup 1.0000x reference)
//
#include <hip/hip_runtime.h>
#include <math.h>

// ---- problem constants ----
// B=8, H=W=D=32, V=32768 per batch, S=64
// outputs (flat, in return order):
//   sampled [8,32,32,32]         -> 262144  @ 0
//   E       [8,3,3]              -> 72      @ 262144
//   coords  [8,32,32,32,3]       -> 786432  @ 262216
//   points_code [8,32768,384]    -> 100663296 @ 1048648
#define OFF_E     262144
#define OFF_COORD 262216
#define OFF_CODE  1048648

#define QUAD 0.19634954084936207f   // 4*pi/64

// ---- ws layout (floats) ----
#define WS_H1 0
#define WS_H2 32768
#define WS_C  98304
#define WS_AB 106496

// ============================================================
// Kernel 1a: hidden layers.  grid 64 = 8 batches x 8 row-groups, 384 thr
// each thread computes 4 adjacent output cols via float4 weight loads.
// ============================================================
__global__ __launch_bounds__(384) void k_hidden(
    const float* __restrict__ F,
    const float* __restrict__ bw1, const float* __restrict__ bb1,
    const float* __restrict__ cw1, const float* __restrict__ cb1,
    float* __restrict__ ws)
{
    __shared__ float sF[8 * 257];   // +1 pad: rows hit distinct banks
    const int blk = blockIdx.x;
    const int b   = blk >> 3;
    const int r0  = (blk & 7) * 8;
    const int tid = threadIdx.x;

    float* wsH1 = ws + WS_H1;
    float* wsH2 = ws + WS_H2;

    const float* Fb = F + ((size_t)b * 64 + r0) * 256;
    for (int i = tid; i < 2048; i += 384) sF[(i >> 8) * 257 + (i & 255)] = Fb[i];
    __syncthreads();

    if (tid < 128) {
        // hidden1: 8 rows x 16 col-quads
        const int row = tid >> 4, k4 = (tid & 15) * 4;
        const float* fr = sF + row * 257;
        float4 acc = *(const float4*)&bb1[k4];
        #pragma unroll 4
        for (int j = 0; j < 256; ++j) {
            const float  f = fr[j];
            const float4 w = *(const float4*)&bw1[j * 64 + k4];
            acc.x = fmaf(f, w.x, acc.x);
            acc.y = fmaf(f, w.y, acc.y);
            acc.z = fmaf(f, w.z, acc.z);
            acc.w = fmaf(f, w.w, acc.w);
        }
        acc.x = fmaxf(acc.x, 0.f); acc.y = fmaxf(acc.y, 0.f);
        acc.z = fmaxf(acc.z, 0.f); acc.w = fmaxf(acc.w, 0.f);
        *(float4*)&wsH1[((size_t)b * 64 + r0 + row) * 64 + k4] = acc;
    } else {
        // hidden2: 8 rows x 32 col-quads
        const int tt  = tid - 128;
        const int row = tt >> 5, k4 = (tt & 31) * 4;
        const float* fr = sF + row * 257;
        float4 acc = *(const float4*)&cb1[k4];
        #pragma unroll 4
        for (int j = 0; j < 256; ++j) {
            const float  f = fr[j];
            const float4 w = *(const float4*)&cw1[j * 128 + k4];
            acc.x = fmaf(f, w.x, acc.x);
            acc.y = fmaf(f, w.y, acc.y);
            acc.z = fmaf(f, w.z, acc.z);
            acc.w = fmaf(f, w.w, acc.w);
        }
        acc.x = fmaxf(acc.x, 0.f); acc.y = fmaxf(acc.y, 0.f);
        acc.z = fmaxf(acc.z, 0.f); acc.w = fmaxf(acc.w, 0.f);
        *(float4*)&wsH2[((size_t)b * 64 + r0 + row) * 128 + k4] = acc;
    }
}

// ============================================================
// Kernel 1b: latent, basis, Y(S2), coeffs, E, A/B.  grid 8, 512 thr
// ============================================================
__global__ __launch_bounds__(512) void k_coeffs(
    const float* __restrict__ ws_in,
    const float* __restrict__ S2,
    const float* __restrict__ bw2, const float* __restrict__ bb2,
    const float* __restrict__ cw2, const float* __restrict__ cb2,
    const float* __restrict__ iw,
    float* __restrict__ ws_out, float* __restrict__ outE)
{
    __shared__ float sH2[64 * 129];             // padded stride
    __shared__ alignas(16) float sLat[64 * 64];
    __shared__ float sY[64 * 16];
    __shared__ float sBas[64 * 3];
    __shared__ float sC[16 * 64];
    __shared__ float sE[9];

    const int b = blockIdx.x, tid = threadIdx.x;
    const float* wsH1 = ws_in + WS_H1;
    const float* wsH2 = ws_in + WS_H2;
    float* wsC  = ws_out + WS_C;
    float* wsAB = ws_out + WS_AB;

    const float* H2b = wsH2 + (size_t)b * 8192;
    for (int i = tid; i < 8192; i += 512) sH2[(i >> 7) * 129 + (i & 127)] = H2b[i];

    // Y basis on sphere points (S2 already unit vectors)
    if (tid < 64) {
        const float x = S2[tid * 3 + 0], y = S2[tid * 3 + 1], z = S2[tid * 3 + 2];
        float* Yv = sY + tid * 16;
        Yv[0]  = 0.28209479f;
        Yv[1]  = 0.48860251f * y;
        Yv[2]  = 0.48860251f * z;
        Yv[3]  = 0.48860251f * x;
        Yv[4]  = 1.09254843f * x * y;
        Yv[5]  = 1.09254843f * y * z;
        Yv[6]  = 0.31539157f * (3.f * z * z - 1.f);
        Yv[7]  = 1.09254843f * x * z;
        Yv[8]  = 0.54627421f * (x * x - y * y);
        Yv[9]  = 0.59004359f * y * (3.f * x * x - y * y);
        Yv[10] = 2.89061144f * x * y * z;
        Yv[11] = 0.45704579f * y * (5.f * z * z - 1.f);
        Yv[12] = 0.37317633f * z * (5.f * z * z - 3.f);
        Yv[13] = 0.45704579f * x * (5.f * z * z - 1.f);
        Yv[14] = 1.44530572f * z * (x * x - y * y);
        Yv[15] = 0.59004359f * x * (x * x - 3.f * y * y);
    }

    // basis = hidden1 @ bw2 + bb2 : [64,3] -> regs (H1 read from global)
    float breg = 0.f;
    if (tid < 192) {
        const int v = tid / 3, c = tid % 3;
        const float* h1 = wsH1 + ((size_t)b * 64 + v) * 64;
        float acc = bb2[c];
        #pragma unroll 8
        for (int k = 0; k < 64; ++k) acc = fmaf(h1[k], bw2[k * 3 + c], acc);
        breg = acc;
    }
    __syncthreads();   // sH2, sY ready

    if (tid < 192) sBas[tid] = breg;

    // latent = hidden2 @ cw2 + cb2 : [64,64], 4 cols/thread via float4
    for (int t = tid; t < 1024; t += 512) {
        const int row = t >> 4, i4 = (t & 15) * 4;
        const float* h2 = sH2 + row * 129;
        float4 acc = *(const float4*)&cb2[i4];
        #pragma unroll 4
        for (int k = 0; k < 128; ++k) {
            const float  h = h2[k];
            const float4 w = *(const float4*)&cw2[k * 64 + i4];
            acc.x = fmaf(h, w.x, acc.x);
            acc.y = fmaf(h, w.y, acc.y);
            acc.z = fmaf(h, w.z, acc.z);
            acc.w = fmaf(h, w.w, acc.w);
        }
        *(float4*)&sLat[row * 64 + i4] = acc;
    }
    __syncthreads();   // sLat, sBas ready

    // coeffs[m,i] = quad * sum_v Y[v,m] * lat[v,i] ; m in [0,16)
    for (int o = tid; o < 1024; o += 512) {
        const int m = o >> 6, i = o & 63;
        float acc = 0.f;
        #pragma unroll 8
        for (int v = 0; v < 64; ++v) acc = fmaf(sY[v * 16 + m], sLat[v * 64 + i], acc);
        acc *= QUAD;
        sC[o] = acc;
        wsC[(size_t)b * 1024 + o] = acc;
    }
    // E row sums (unnormalized)
    if (tid < 9) {
        const int m = tid / 3, c = tid % 3;
        float acc = 0.f;
        for (int v = 0; v < 64; ++v) acc = fmaf(sY[v * 16 + 1 + m], sBas[v * 3 + c], acc);
        sE[tid] = acc * QUAD;
    }
    __syncthreads();   // sC, sE ready

    if (tid < 9) {
        const int m = tid / 3;
        const float e0 = sE[m * 3 + 0], e1 = sE[m * 3 + 1], e2 = sE[m * 3 + 2];
        const float n = sqrtf(e0 * e0 + e1 * e1 + e2 * e2);
        outE[b * 9 + tid] = sE[tid] / fmaxf(n, 1e-6f);
    }
    // A/B fold of points_inv @ iw
    if (tid < 18) {
        const int which = tid / 9, mc = tid % 9;
        const int m = mc / 3, c = mc % 3;
        float acc = 0.f;
        #pragma unroll 8
        for (int i = 0; i < 64; ++i)
            acc = fmaf(sC[(1 + m) * 64 + i], iw[(2 * i + which) * 3 + c], acc);
        wsAB[b * 18 + tid] = acc;
    }
}

// ============================================================
// Kernel 2: per-point monomials, points_code, coords, grid-sample.
// grid 2048 = 8 batches x 256 groups of 128 points ; 384 threads (6 waves)
// sZ row layout (20 floats, 80B, 16B-aligned rows):
//   f0..f2 = Y1*r (m1..3), f3 = r^2          -> one b128 for the l1 waves
//   f4..f10 = Y3*r^3 (m9..15)                -> b128 @f4 + b64 @f8 + b32 @f10
//   f12..f16 = Y2*r^2 (m4..8)                -> b128 @f12 + b32 @f16
// ============================================================
__global__ __launch_bounds__(384) void k_points(
    const float* __restrict__ x, const float* __restrict__ dens,
    const float* __restrict__ ws, const float* __restrict__ ib,
    float* __restrict__ out)
{
    __shared__ alignas(16) float sC[16 * 64];
    __shared__ float sAB[18];
    __shared__ alignas(16) float sZ[128 * 20];

    const int blk = blockIdx.x;       // b*256 + group
    const int b   = blk >> 8;
    const int v0  = (blk & 255) * 128;
    const int tid = threadIdx.x;

    const float* wsC  = ws + WS_C;
    const float* wsAB = ws + WS_AB;

    if (tid < 256) ((float4*)sC)[tid] = ((const float4*)(wsC + (size_t)b * 1024))[tid];
    if (tid < 18) sAB[tid] = wsAB[b * 18 + tid];

    // ---- phase A (pre-barrier): monomials only, 2 waves ----
    float z1 = 0.f, z2 = 0.f, z3 = 0.f, r2 = 0.f;
    size_t g = 0;
    if (tid < 128) {
        const int v = v0 + tid;
        g = (size_t)b * 32768 + v;
        const float px = x[g * 3 + 0], py = x[g * 3 + 1], pz = x[g * 3 + 2];
        r2 = px * px + py * py + pz * pz;
        const float r   = sqrtf(r2);
        const float inv = 1.f / fmaxf(r, 1e-6f);
        const float ux = px * inv, uy = py * inv, uz = pz * inv;
        float* Z = sZ + tid * 20;
        z1 = 0.48860251f * uy * r;
        z2 = 0.48860251f * uz * r;
        z3 = 0.48860251f * ux * r;
        Z[0] = z1; Z[1] = z2; Z[2] = z3; Z[3] = r2;
        const float r3 = r2 * r;
        Z[4]  = 0.59004359f * uy * (3.f * ux * ux - uy * uy) * r3;
        Z[5]  = 2.89061144f * ux * uy * uz * r3;
        Z[6]  = 0.45704579f * uy * (5.f * uz * uz - 1.f) * r3;
        Z[7]  = 0.37317633f * uz * (5.f * uz * uz - 3.f) * r3;
        Z[8]  = 0.45704579f * ux * (5.f * uz * uz - 1.f) * r3;
        Z[9]  = 1.44530572f * uz * (ux * ux - uy * uy) * r3;
        Z[10] = 0.59004359f * ux * (ux * ux - 3.f * uy * uy) * r3;
        Z[12] = 1.09254843f * ux * uy * r2;
        Z[13] = 1.09254843f * uy * uz * r2;
        Z[14] = 0.31539157f * (3.f * uz * uz - 1.f) * r2;
        Z[15] = 1.09254843f * ux * uz * r2;
        Z[16] = 0.54627421f * (ux * ux - uy * uy) * r2;
    }
    __syncthreads();

    // ---- phase C: one channel per thread, all 6 waves ----
    const int c = tid;
    float* po = out + OFF_CODE + ((size_t)b * 32768 + v0) * 384 + c;
    if (c < 128) {
        // l=0: C0[i]*Y00 (* r^2 if j)
        const float cr = sC[c >> 1] * 0.28209479f;
        const bool  jr = (c & 1) != 0;
        #pragma unroll 4
        for (int v = 0; v < 128; ++v) {
            const float r2v = sZ[v * 20 + 3];
            const float a = jr ? cr * r2v : cr;
            po[(size_t)v * 384] = a;
        }
    } else if (c < 256) {
        // l=1: dot3 over (z1,z2,z3) packed with r2 -> single b128 per row
        const int  i  = (c - 128) >> 1;
        const bool jr = (c & 1) != 0;
        const float c0 = sC[1 * 64 + i], c1 = sC[2 * 64 + i], c2 = sC[3 * 64 + i];
        #pragma unroll 4
        for (int v = 0; v < 128; ++v) {
            const float4 z = *(const float4*)(sZ + v * 20);
            float a = c0 * z.x;
            a = fmaf(c1, z.y, a);
            a = fmaf(c2, z.z, a);
            a = jr ? a * z.w : a;
            po[(size_t)v * 384] = a;
        }
    } else if (c < 320) {
        // l=2: dot5
        const int i = c - 256;
        const float c0 = sC[4 * 64 + i], c1 = sC[5 * 64 + i], c2 = sC[6 * 64 + i];
        const float c3 = sC[7 * 64 + i], c4 = sC[8 * 64 + i];
        #pragma unroll 4
        for (int v = 0; v < 128; ++v) {
            const float4 z  = *(const float4*)(sZ + v * 20 + 12);
            const float  z4 = sZ[v * 20 + 16];
            float a = c0 * z.x;
            a = fmaf(c1, z.y, a);
            a = fmaf(c2, z.z, a);
            a = fmaf(c3, z.w, a);
            a = fmaf(c4, z4,  a);
            po[(size_t)v * 384] = a;
        }
    } else {
        // l=3: dot7
        const int i = c - 320;
        const float c0 = sC[ 9 * 64 + i], c1 = sC[10 * 64 + i], c2 = sC[11 * 64 + i];
        const float c3 = sC[12 * 64 + i], c4 = sC[13 * 64 + i], c5 = sC[14 * 64 + i];
        const float c6 = sC[15 * 64 + i];
        #pragma unroll 4
        for (int v = 0; v < 128; ++v) {
            const float4 za = *(const float4*)(sZ + v * 20 + 4);
            const float2 zb = *(const float2*)(sZ + v * 20 + 8);
            const float  zc = sZ[v * 20 + 10];
            float a = c0 * za.x;
            a = fmaf(c1, za.y, a);
            a = fmaf(c2, za.z, a);
            a = fmaf(c3, za.w, a);
            a = fmaf(c4, zb.x, a);
            a = fmaf(c5, zb.y, a);
            a = fmaf(c6, zc,  a);
            po[(size_t)v * 384] = a;
        }
    }

    // ---- phase B (post): coords + grid-sample, overlapped with other waves ----
    if (tid < 128) {
        const float zr0 = z1, zr1 = z2, zr2 = z3;
        float pt[3];
        #pragma unroll
        for (int cc = 0; cc < 3; ++cc) {
            float acc = ib[cc];
            acc = fmaf(zr0, sAB[0 * 3 + cc] + r2 * sAB[9 + 0 * 3 + cc], acc);
            acc = fmaf(zr1, sAB[1 * 3 + cc] + r2 * sAB[9 + 1 * 3 + cc], acc);
            acc = fmaf(zr2, sAB[2 * 3 + cc] + r2 * sAB[9 + 2 * 3 + cc], acc);
            pt[cc] = acc;
            out[OFF_COORD + g * 3 + cc] = acc;
        }

        // grid_sample_3d: align_corners=True, zeros padding; vol 32^3
        const float ix = (pt[0] + 1.f) * 0.5f * 31.f;
        const float iy = (pt[1] + 1.f) * 0.5f * 31.f;
        const float iz = (pt[2] + 1.f) * 0.5f * 31.f;
        const float x0f = floorf(ix), y0f = floorf(iy), z0f = floorf(iz);
        const float wx = ix - x0f, wy = iy - y0f, wz = iz - z0f;
        const int x0 = (int)x0f, y0 = (int)y0f, z0 = (int)z0f;
        const float* volb = dens + (size_t)b * 32768;
        float s = 0.f;
        #pragma unroll
        for (int dz = 0; dz < 2; ++dz) {
            const int zi = z0 + dz;
            const float wzz = dz ? wz : 1.f - wz;
            #pragma unroll
            for (int dy = 0; dy < 2; ++dy) {
                const int yi = y0 + dy;
                const float wyy = dy ? wy : 1.f - wy;
                #pragma unroll
                for (int dx = 0; dx < 2; ++dx) {
                    const int xi = x0 + dx;
                    const float wxx = dx ? wx : 1.f - wx;
                    if (zi >= 0 && zi < 32 && yi >= 0 && yi < 32 && xi >= 0 && xi < 32)
                        s += wzz * wyy * wxx * volb[zi * 1024 + yi * 32 + xi];
                }
            }
        }
        out[g] = s;
    }
}

// ============================================================
extern "C" void kernel_launch(void* const* d_in, const int* in_sizes, int n_in,
                              void* d_out, int out_size, void* d_ws, size_t ws_size,
                              hipStream_t stream) {
    const float* x    = (const float*)d_in[0];
    const float* dens = (const float*)d_in[1];
    const float* F    = (const float*)d_in[2];
    const float* S2   = (const float*)d_in[3];
    const float* bw1  = (const float*)d_in[4];
    const float* bb1  = (const float*)d_in[5];
    const float* bw2  = (const float*)d_in[6];
    const float* bb2  = (const float*)d_in[7];
    const float* cw1  = (const float*)d_in[8];
    const float* cb1  = (const float*)d_in[9];
    const float* cw2  = (const float*)d_in[10];
    const float* cb2  = (const float*)d_in[11];
    const float* iw   = (const float*)d_in[12];
    const float* ib   = (const float*)d_in[13];
    float* out = (float*)d_out;
    float* ws  = (float*)d_ws;

    k_hidden<<<64,   384, 0, stream>>>(F, bw1, bb1, cw1, cb1, ws);
    k_coeffs<<<8,    512, 0, stream>>>(ws, S2, bw2, bb2, cw2, cb2, iw, ws, out + OFF_E);
    k_points<<<2048, 384, 0, stream>>>(x, dens, ws, ib, out);
}

// Round 2
// 556.529 us; speedup vs baseline: 1.0566x; 1.0566x over previous
//
#include <hip/hip_runtime.h>
#include <math.h>

// ---- problem constants ----
// B=8, H=W=D=32, V=32768 per batch, S=64
// outputs (flat, in return order):
//   sampled [8,32,32,32]         -> 262144  @ 0
//   E       [8,3,3]              -> 72      @ 262144
//   coords  [8,32,32,32,3]       -> 786432  @ 262216
//   points_code [8,32768,384]    -> 100663296 @ 1048648
#define OFF_E     262144
#define OFF_COORD 262216
#define OFF_CODE  1048648

#define QUAD 0.19634954084936207f   // 4*pi/64

// ---- ws layout (floats) ----
#define WS_H1 0
#define WS_H2 32768
#define WS_C  98304
#define WS_AB 106496

// ============================================================
// Kernel 1a: hidden layers.  grid 64 = 8 batches x 8 row-groups, 384 thr
// ============================================================
__global__ __launch_bounds__(384) void k_hidden(
    const float* __restrict__ F,
    const float* __restrict__ bw1, const float* __restrict__ bb1,
    const float* __restrict__ cw1, const float* __restrict__ cb1,
    float* __restrict__ ws)
{
    __shared__ float sF[8 * 257];   // +1 pad: rows hit distinct banks
    const int blk = blockIdx.x;
    const int b   = blk >> 3;
    const int r0  = (blk & 7) * 8;
    const int tid = threadIdx.x;

    float* wsH1 = ws + WS_H1;
    float* wsH2 = ws + WS_H2;

    const float* Fb = F + ((size_t)b * 64 + r0) * 256;
    for (int i = tid; i < 2048; i += 384) sF[(i >> 8) * 257 + (i & 255)] = Fb[i];
    __syncthreads();

    if (tid < 128) {
        // hidden1: 8 rows x 16 col-quads
        const int row = tid >> 4, k4 = (tid & 15) * 4;
        const float* fr = sF + row * 257;
        float4 acc = *(const float4*)&bb1[k4];
        #pragma unroll 4
        for (int j = 0; j < 256; ++j) {
            const float  f = fr[j];
            const float4 w = *(const float4*)&bw1[j * 64 + k4];
            acc.x = fmaf(f, w.x, acc.x);
            acc.y = fmaf(f, w.y, acc.y);
            acc.z = fmaf(f, w.z, acc.z);
            acc.w = fmaf(f, w.w, acc.w);
        }
        acc.x = fmaxf(acc.x, 0.f); acc.y = fmaxf(acc.y, 0.f);
        acc.z = fmaxf(acc.z, 0.f); acc.w = fmaxf(acc.w, 0.f);
        *(float4*)&wsH1[((size_t)b * 64 + r0 + row) * 64 + k4] = acc;
    } else {
        // hidden2: 8 rows x 32 col-quads
        const int tt  = tid - 128;
        const int row = tt >> 5, k4 = (tt & 31) * 4;
        const float* fr = sF + row * 257;
        float4 acc = *(const float4*)&cb1[k4];
        #pragma unroll 4
        for (int j = 0; j < 256; ++j) {
            const float  f = fr[j];
            const float4 w = *(const float4*)&cw1[j * 128 + k4];
            acc.x = fmaf(f, w.x, acc.x);
            acc.y = fmaf(f, w.y, acc.y);
            acc.z = fmaf(f, w.z, acc.z);
            acc.w = fmaf(f, w.w, acc.w);
        }
        acc.x = fmaxf(acc.x, 0.f); acc.y = fmaxf(acc.y, 0.f);
        acc.z = fmaxf(acc.z, 0.f); acc.w = fmaxf(acc.w, 0.f);
        *(float4*)&wsH2[((size_t)b * 64 + r0 + row) * 128 + k4] = acc;
    }
}

// ============================================================
// Kernel 1b: latent, basis, Y(S2), coeffs, E, A/B.  grid 8, 512 thr
// ============================================================
__global__ __launch_bounds__(512) void k_coeffs(
    const float* __restrict__ ws_in,
    const float* __restrict__ S2,
    const float* __restrict__ bw2, const float* __restrict__ bb2,
    const float* __restrict__ cw2, const float* __restrict__ cb2,
    const float* __restrict__ iw,
    float* __restrict__ ws_out, float* __restrict__ outE)
{
    __shared__ float sH2[64 * 129];             // padded stride
    __shared__ alignas(16) float sLat[64 * 64];
    __shared__ float sY[64 * 16];
    __shared__ float sBas[64 * 3];
    __shared__ float sC[16 * 64];
    __shared__ float sE[9];

    const int b = blockIdx.x, tid = threadIdx.x;
    const float* wsH1 = ws_in + WS_H1;
    const float* wsH2 = ws_in + WS_H2;
    float* wsC  = ws_out + WS_C;
    float* wsAB = ws_out + WS_AB;

    const float* H2b = wsH2 + (size_t)b * 8192;
    for (int i = tid; i < 8192; i += 512) sH2[(i >> 7) * 129 + (i & 127)] = H2b[i];

    // Y basis on sphere points (S2 already unit vectors)
    if (tid < 64) {
        const float x = S2[tid * 3 + 0], y = S2[tid * 3 + 1], z = S2[tid * 3 + 2];
        float* Yv = sY + tid * 16;
        Yv[0]  = 0.28209479f;
        Yv[1]  = 0.48860251f * y;
        Yv[2]  = 0.48860251f * z;
        Yv[3]  = 0.48860251f * x;
        Yv[4]  = 1.09254843f * x * y;
        Yv[5]  = 1.09254843f * y * z;
        Yv[6]  = 0.31539157f * (3.f * z * z - 1.f);
        Yv[7]  = 1.09254843f * x * z;
        Yv[8]  = 0.54627421f * (x * x - y * y);
        Yv[9]  = 0.59004359f * y * (3.f * x * x - y * y);
        Yv[10] = 2.89061144f * x * y * z;
        Yv[11] = 0.45704579f * y * (5.f * z * z - 1.f);
        Yv[12] = 0.37317633f * z * (5.f * z * z - 3.f);
        Yv[13] = 0.45704579f * x * (5.f * z * z - 1.f);
        Yv[14] = 1.44530572f * z * (x * x - y * y);
        Yv[15] = 0.59004359f * x * (x * x - 3.f * y * y);
    }

    // basis = hidden1 @ bw2 + bb2 : [64,3] -> regs (H1 read from global)
    float breg = 0.f;
    if (tid < 192) {
        const int v = tid / 3, c = tid % 3;
        const float* h1 = wsH1 + ((size_t)b * 64 + v) * 64;
        float acc = bb2[c];
        #pragma unroll 8
        for (int k = 0; k < 64; ++k) acc = fmaf(h1[k], bw2[k * 3 + c], acc);
        breg = acc;
    }
    __syncthreads();   // sH2, sY ready

    if (tid < 192) sBas[tid] = breg;

    // latent = hidden2 @ cw2 + cb2 : [64,64], 4 cols/thread via float4
    for (int t = tid; t < 1024; t += 512) {
        const int row = t >> 4, i4 = (t & 15) * 4;
        const float* h2 = sH2 + row * 129;
        float4 acc = *(const float4*)&cb2[i4];
        #pragma unroll 4
        for (int k = 0; k < 128; ++k) {
            const float  h = h2[k];
            const float4 w = *(const float4*)&cw2[k * 64 + i4];
            acc.x = fmaf(h, w.x, acc.x);
            acc.y = fmaf(h, w.y, acc.y);
            acc.z = fmaf(h, w.z, acc.z);
            acc.w = fmaf(h, w.w, acc.w);
        }
        *(float4*)&sLat[row * 64 + i4] = acc;
    }
    __syncthreads();   // sLat, sBas ready

    // coeffs[m,i] = quad * sum_v Y[v,m] * lat[v,i] ; m in [0,16)
    for (int o = tid; o < 1024; o += 512) {
        const int m = o >> 6, i = o & 63;
        float acc = 0.f;
        #pragma unroll 8
        for (int v = 0; v < 64; ++v) acc = fmaf(sY[v * 16 + m], sLat[v * 64 + i], acc);
        acc *= QUAD;
        sC[o] = acc;
        wsC[(size_t)b * 1024 + o] = acc;
    }
    // E row sums (unnormalized)
    if (tid < 9) {
        const int m = tid / 3, c = tid % 3;
        float acc = 0.f;
        for (int v = 0; v < 64; ++v) acc = fmaf(sY[v * 16 + 1 + m], sBas[v * 3 + c], acc);
        sE[tid] = acc * QUAD;
    }
    __syncthreads();   // sC, sE ready

    if (tid < 9) {
        const int m = tid / 3;
        const float e0 = sE[m * 3 + 0], e1 = sE[m * 3 + 1], e2 = sE[m * 3 + 2];
        const float n = sqrtf(e0 * e0 + e1 * e1 + e2 * e2);
        outE[b * 9 + tid] = sE[tid] / fmaxf(n, 1e-6f);
    }
    // A/B fold of points_inv @ iw
    if (tid < 18) {
        const int which = tid / 9, mc = tid % 9;
        const int m = mc / 3, c = mc % 3;
        float acc = 0.f;
        #pragma unroll 8
        for (int i = 0; i < 64; ++i)
            acc = fmaf(sC[(1 + m) * 64 + i], iw[(2 * i + which) * 3 + c], acc);
        wsAB[b * 18 + tid] = acc;
    }
}

// ============================================================
// Kernel 2: per-point monomials, points_code, coords, grid-sample.
// grid 2048 = 8 batches x 256 groups of 128 points ; 384 threads (6 waves)
//
// phase C thread map (each thread owns a QUAD of 4 adjacent channels and a
// 32-point v-slice; one float4 store per point-row -> 1024 B per wave store):
//   waves 0-1 (tid 0..127):   l0  quads q=tid&31 (ch 4q..4q+3),    vh=tid>>5
//   waves 2-3 (tid 128..255): l1  quads q (ch 128+4q..),           vh=(tid-128)>>5
//   wave 4   (tid 256..319):  l2  quads q=ln&15 (ch 256+4q..),     vh=ln>>4
//   wave 5   (tid 320..383):  l3  quads q=ln&15 (ch 320+4q..),     vh=ln>>4
//
// sZ row layout (20 floats, 80B, 16B-aligned rows):
//   f0..f2 = Y1*r (m1..3), f3 = r^2          -> one b128 for l1
//   f4..f10 = Y3*r^3 (m9..15)                -> b128 @f4 + b64 @f8 + b32 @f10
//   f12..f16 = Y2*r^2 (m4..8)                -> b128 @f12 + b32 @f16
// ============================================================
__global__ __launch_bounds__(384) void k_points(
    const float* __restrict__ x, const float* __restrict__ dens,
    const float* __restrict__ ws, const float* __restrict__ ib,
    float* __restrict__ out)
{
    __shared__ alignas(16) float sC[16 * 64];
    __shared__ float sAB[18];
    __shared__ alignas(16) float sZ[128 * 20];

    const int blk = blockIdx.x;       // b*256 + group
    const int b   = blk >> 8;
    const int v0  = (blk & 255) * 128;
    const int tid = threadIdx.x;

    const float* wsC  = ws + WS_C;
    const float* wsAB = ws + WS_AB;

    if (tid < 256) ((float4*)sC)[tid] = ((const float4*)(wsC + (size_t)b * 1024))[tid];
    if (tid < 18) sAB[tid] = wsAB[b * 18 + tid];

    // ---- phase A (pre-barrier): monomials only, waves 0-1 ----
    float z1 = 0.f, z2 = 0.f, z3 = 0.f, r2 = 0.f;
    size_t g = 0;
    if (tid < 128) {
        const int v = v0 + tid;
        g = (size_t)b * 32768 + v;
        const float px = x[g * 3 + 0], py = x[g * 3 + 1], pz = x[g * 3 + 2];
        r2 = px * px + py * py + pz * pz;
        const float r   = sqrtf(r2);
        const float inv = 1.f / fmaxf(r, 1e-6f);
        const float ux = px * inv, uy = py * inv, uz = pz * inv;
        float* Z = sZ + tid * 20;
        z1 = 0.48860251f * uy * r;
        z2 = 0.48860251f * uz * r;
        z3 = 0.48860251f * ux * r;
        Z[0] = z1; Z[1] = z2; Z[2] = z3; Z[3] = r2;
        const float r3 = r2 * r;
        Z[4]  = 0.59004359f * uy * (3.f * ux * ux - uy * uy) * r3;
        Z[5]  = 2.89061144f * ux * uy * uz * r3;
        Z[6]  = 0.45704579f * uy * (5.f * uz * uz - 1.f) * r3;
        Z[7]  = 0.37317633f * uz * (5.f * uz * uz - 3.f) * r3;
        Z[8]  = 0.45704579f * ux * (5.f * uz * uz - 1.f) * r3;
        Z[9]  = 1.44530572f * uz * (ux * ux - uy * uy) * r3;
        Z[10] = 0.59004359f * ux * (ux * ux - 3.f * uy * uy) * r3;
        Z[12] = 1.09254843f * ux * uy * r2;
        Z[13] = 1.09254843f * uy * uz * r2;
        Z[14] = 0.31539157f * (3.f * uz * uz - 1.f) * r2;
        Z[15] = 1.09254843f * ux * uz * r2;
        Z[16] = 0.54627421f * (ux * ux - uy * uy) * r2;
    }
    __syncthreads();

    // ---- phase C: quad-per-thread, float4 stores ----
    const size_t rowbase = OFF_CODE + ((size_t)b * 32768 + v0) * 384;
    if (tid < 128) {
        // l0: vals {a, a*r2, b, b*r2}
        const int q = tid & 31, vh = tid >> 5;
        const float ca = sC[2 * q]     * 0.28209479f;
        const float cb = sC[2 * q + 1] * 0.28209479f;
        const float* zr = sZ + (vh * 32) * 20 + 3;
        float* po = out + rowbase + (size_t)(vh * 32) * 384 + 4 * q;
        #pragma unroll 4
        for (int vi = 0; vi < 32; ++vi) {
            const float r2v = zr[(size_t)vi * 20];
            float4 o;
            o.x = ca; o.y = ca * r2v; o.z = cb; o.w = cb * r2v;
            *(float4*)po = o;
            po += 384;
        }
    } else if (tid < 256) {
        // l1: two dot3, vals {d0, d0*r2, d1, d1*r2}
        const int u = tid - 128, q = u & 31, vh = u >> 5;
        const float c00 = sC[64 + 2 * q],     c01 = sC[128 + 2 * q],     c02 = sC[192 + 2 * q];
        const float c10 = sC[64 + 2 * q + 1], c11 = sC[128 + 2 * q + 1], c12 = sC[192 + 2 * q + 1];
        const float* zr = sZ + (vh * 32) * 20;
        float* po = out + rowbase + (size_t)(vh * 32) * 384 + 128 + 4 * q;
        #pragma unroll 4
        for (int vi = 0; vi < 32; ++vi) {
            const float4 z = *(const float4*)(zr + (size_t)vi * 20);
            float d0 = c00 * z.x; d0 = fmaf(c01, z.y, d0); d0 = fmaf(c02, z.z, d0);
            float d1 = c10 * z.x; d1 = fmaf(c11, z.y, d1); d1 = fmaf(c12, z.z, d1);
            float4 o;
            o.x = d0; o.y = d0 * z.w; o.z = d1; o.w = d1 * z.w;
            *(float4*)po = o;
            po += 384;
        }
    } else if (tid < 320) {
        // l2: four dot5
        const int ln = tid & 63, q = ln & 15, vh = ln >> 4;
        const int i0 = 4 * q;
        float cf[5][4];
        #pragma unroll
        for (int m = 0; m < 5; ++m)
            #pragma unroll
            for (int k = 0; k < 4; ++k) cf[m][k] = sC[(4 + m) * 64 + i0 + k];
        const float* zr = sZ + (vh * 32) * 20;
        float* po = out + rowbase + (size_t)(vh * 32) * 384 + 256 + i0;
        #pragma unroll 4
        for (int vi = 0; vi < 32; ++vi) {
            const float4 za = *(const float4*)(zr + (size_t)vi * 20 + 12);
            const float  zb = zr[(size_t)vi * 20 + 16];
            float4 o;
            float* a = &o.x;
            #pragma unroll
            for (int k = 0; k < 4; ++k) {
                float acc = cf[0][k] * za.x;
                acc = fmaf(cf[1][k], za.y, acc);
                acc = fmaf(cf[2][k], za.z, acc);
                acc = fmaf(cf[3][k], za.w, acc);
                acc = fmaf(cf[4][k], zb,   acc);
                a[k] = acc;
            }
            *(float4*)po = o;
            po += 384;
        }
    } else {
        // l3: four dot7
        const int ln = tid & 63, q = ln & 15, vh = ln >> 4;
        const int i0 = 4 * q;
        float cf[7][4];
        #pragma unroll
        for (int m = 0; m < 7; ++m)
            #pragma unroll
            for (int k = 0; k < 4; ++k) cf[m][k] = sC[(9 + m) * 64 + i0 + k];
        const float* zr = sZ + (vh * 32) * 20;
        float* po = out + rowbase + (size_t)(vh * 32) * 384 + 320 + i0;
        #pragma unroll 2
        for (int vi = 0; vi < 32; ++vi) {
            const float4 za = *(const float4*)(zr + (size_t)vi * 20 + 4);
            const float2 zb = *(const float2*)(zr + (size_t)vi * 20 + 8);
            const float  zc = zr[(size_t)vi * 20 + 10];
            float4 o;
            float* a = &o.x;
            #pragma unroll
            for (int k = 0; k < 4; ++k) {
                float acc = cf[0][k] * za.x;
                acc = fmaf(cf[1][k], za.y, acc);
                acc = fmaf(cf[2][k], za.z, acc);
                acc = fmaf(cf[3][k], za.w, acc);
                acc = fmaf(cf[4][k], zb.x, acc);
                acc = fmaf(cf[5][k], zb.y, acc);
                acc = fmaf(cf[6][k], zc,   acc);
                a[k] = acc;
            }
            *(float4*)po = o;
            po += 384;
        }
    }

    // ---- phase B (post): coords + grid-sample, overlapped with other waves ----
    if (tid < 128) {
        const float zr0 = z1, zr1 = z2, zr2 = z3;
        float pt[3];
        #pragma unroll
        for (int cc = 0; cc < 3; ++cc) {
            float acc = ib[cc];
            acc = fmaf(zr0, sAB[0 * 3 + cc] + r2 * sAB[9 + 0 * 3 + cc], acc);
            acc = fmaf(zr1, sAB[1 * 3 + cc] + r2 * sAB[9 + 1 * 3 + cc], acc);
            acc = fmaf(zr2, sAB[2 * 3 + cc] + r2 * sAB[9 + 2 * 3 + cc], acc);
            pt[cc] = acc;
            out[OFF_COORD + g * 3 + cc] = acc;
        }

        // grid_sample_3d: align_corners=True, zeros padding; vol 32^3
        const float ix = (pt[0] + 1.f) * 0.5f * 31.f;
        const float iy = (pt[1] + 1.f) * 0.5f * 31.f;
        const float iz = (pt[2] + 1.f) * 0.5f * 31.f;
        const float x0f = floorf(ix), y0f = floorf(iy), z0f = floorf(iz);
        const float wx = ix - x0f, wy = iy - y0f, wz = iz - z0f;
        const int x0 = (int)x0f, y0 = (int)y0f, z0 = (int)z0f;
        const float* volb = dens + (size_t)b * 32768;
        float s = 0.f;
        #pragma unroll
        for (int dz = 0; dz < 2; ++dz) {
            const int zi = z0 + dz;
            const float wzz = dz ? wz : 1.f - wz;
            #pragma unroll
            for (int dy = 0; dy < 2; ++dy) {
                const int yi = y0 + dy;
                const float wyy = dy ? wy : 1.f - wy;
                #pragma unroll
                for (int dx = 0; dx < 2; ++dx) {
                    const int xi = x0 + dx;
                    const float wxx = dx ? wx : 1.f - wx;
                    if (zi >= 0 && zi < 32 && yi >= 0 && yi < 32 && xi >= 0 && xi < 32)
                        s += wzz * wyy * wxx * volb[zi * 1024 + yi * 32 + xi];
                }
            }
        }
        out[g] = s;
    }
}

// ============================================================
extern "C" void kernel_launch(void* const* d_in, const int* in_sizes, int n_in,
                              void* d_out, int out_size, void* d_ws, size_t ws_size,
                              hipStream_t stream) {
    const float* x    = (const float*)d_in[0];
    const float* dens = (const float*)d_in[1];
    const float* F    = (const float*)d_in[2];
    const float* S2   = (const float*)d_in[3];
    const float* bw1  = (const float*)d_in[4];
    const float* bb1  = (const float*)d_in[5];
    const float* bw2  = (const float*)d_in[6];
    const float* bb2  = (const float*)d_in[7];
    const float* cw1  = (const float*)d_in[8];
    const float* cb1  = (const float*)d_in[9];
    const float* cw2  = (const float*)d_in[10];
    const float* cb2  = (const float*)d_in[11];
    const float* iw   = (const float*)d_in[12];
    const float* ib   = (const float*)d_in[13];
    float* out = (float*)d_out;
    float* ws  = (float*)d_ws;

    k_hidden<<<64,   384, 0, stream>>>(F, bw1, bb1, cw1, cb1, ws);
    k_coeffs<<<8,    512, 0, stream>>>(ws, S2, bw2, bb2, cw2, cb2, iw, ws, out + OFF_E);
    k_points<<<2048, 384, 0, stream>>>(x, dens, ws, ib, out);
}

// Round 3
// 550.993 us; speedup vs baseline: 1.0672x; 1.0100x over previous
//
#include <hip/hip_runtime.h>
#include <math.h>

// ---- problem constants ----
// B=8, H=W=D=32, V=32768 per batch, S=64
// outputs (flat, in return order):
//   sampled [8,32,32,32]         -> 262144  @ 0
//   E       [8,3,3]              -> 72      @ 262144
//   coords  [8,32,32,32,3]       -> 786432  @ 262216
//   points_code [8,32768,384]    -> 100663296 @ 1048648
#define OFF_E     262144
#define OFF_COORD 262216
#define OFF_CODE  1048648

#define QUAD 0.19634954084936207f   // 4*pi/64

// ---- ws layout (floats) ----
#define WS_H1 0
#define WS_H2 32768
#define WS_C  98304
#define WS_AB 106496

// ============================================================
// Kernel 1a: hidden layers.  grid 64 = 8 batches x 8 row-groups, 384 thr
// ============================================================
__global__ __launch_bounds__(384) void k_hidden(
    const float* __restrict__ F,
    const float* __restrict__ bw1, const float* __restrict__ bb1,
    const float* __restrict__ cw1, const float* __restrict__ cb1,
    float* __restrict__ ws)
{
    __shared__ float sF[8 * 257];   // +1 pad: rows hit distinct banks
    const int blk = blockIdx.x;
    const int b   = blk >> 3;
    const int r0  = (blk & 7) * 8;
    const int tid = threadIdx.x;

    float* wsH1 = ws + WS_H1;
    float* wsH2 = ws + WS_H2;

    const float* Fb = F + ((size_t)b * 64 + r0) * 256;
    for (int i = tid; i < 2048; i += 384) sF[(i >> 8) * 257 + (i & 255)] = Fb[i];
    __syncthreads();

    if (tid < 128) {
        // hidden1: 8 rows x 16 col-quads
        const int row = tid >> 4, k4 = (tid & 15) * 4;
        const float* fr = sF + row * 257;
        float4 acc = *(const float4*)&bb1[k4];
        #pragma unroll 4
        for (int j = 0; j < 256; ++j) {
            const float  f = fr[j];
            const float4 w = *(const float4*)&bw1[j * 64 + k4];
            acc.x = fmaf(f, w.x, acc.x);
            acc.y = fmaf(f, w.y, acc.y);
            acc.z = fmaf(f, w.z, acc.z);
            acc.w = fmaf(f, w.w, acc.w);
        }
        acc.x = fmaxf(acc.x, 0.f); acc.y = fmaxf(acc.y, 0.f);
        acc.z = fmaxf(acc.z, 0.f); acc.w = fmaxf(acc.w, 0.f);
        *(float4*)&wsH1[((size_t)b * 64 + r0 + row) * 64 + k4] = acc;
    } else {
        // hidden2: 8 rows x 32 col-quads
        const int tt  = tid - 128;
        const int row = tt >> 5, k4 = (tt & 31) * 4;
        const float* fr = sF + row * 257;
        float4 acc = *(const float4*)&cb1[k4];
        #pragma unroll 4
        for (int j = 0; j < 256; ++j) {
            const float  f = fr[j];
            const float4 w = *(const float4*)&cw1[j * 128 + k4];
            acc.x = fmaf(f, w.x, acc.x);
            acc.y = fmaf(f, w.y, acc.y);
            acc.z = fmaf(f, w.z, acc.z);
            acc.w = fmaf(f, w.w, acc.w);
        }
        acc.x = fmaxf(acc.x, 0.f); acc.y = fmaxf(acc.y, 0.f);
        acc.z = fmaxf(acc.z, 0.f); acc.w = fmaxf(acc.w, 0.f);
        *(float4*)&wsH2[((size_t)b * 64 + r0 + row) * 128 + k4] = acc;
    }
}

// ============================================================
// Kernel 1b: latent, basis, Y(S2), coeffs, E, A/B.  grid 8, 512 thr
// ============================================================
__global__ __launch_bounds__(512) void k_coeffs(
    const float* __restrict__ ws_in,
    const float* __restrict__ S2,
    const float* __restrict__ bw2, const float* __restrict__ bb2,
    const float* __restrict__ cw2, const float* __restrict__ cb2,
    const float* __restrict__ iw,
    float* __restrict__ ws_out, float* __restrict__ outE)
{
    __shared__ float sH2[64 * 129];             // padded stride
    __shared__ alignas(16) float sLat[64 * 64];
    __shared__ float sY[64 * 16];
    __shared__ float sBas[64 * 3];
    __shared__ float sC[16 * 64];
    __shared__ float sE[9];

    const int b = blockIdx.x, tid = threadIdx.x;
    const float* wsH1 = ws_in + WS_H1;
    const float* wsH2 = ws_in + WS_H2;
    float* wsC  = ws_out + WS_C;
    float* wsAB = ws_out + WS_AB;

    const float* H2b = wsH2 + (size_t)b * 8192;
    for (int i = tid; i < 8192; i += 512) sH2[(i >> 7) * 129 + (i & 127)] = H2b[i];

    // Y basis on sphere points (S2 already unit vectors)
    if (tid < 64) {
        const float x = S2[tid * 3 + 0], y = S2[tid * 3 + 1], z = S2[tid * 3 + 2];
        float* Yv = sY + tid * 16;
        Yv[0]  = 0.28209479f;
        Yv[1]  = 0.48860251f * y;
        Yv[2]  = 0.48860251f * z;
        Yv[3]  = 0.48860251f * x;
        Yv[4]  = 1.09254843f * x * y;
        Yv[5]  = 1.09254843f * y * z;
        Yv[6]  = 0.31539157f * (3.f * z * z - 1.f);
        Yv[7]  = 1.09254843f * x * z;
        Yv[8]  = 0.54627421f * (x * x - y * y);
        Yv[9]  = 0.59004359f * y * (3.f * x * x - y * y);
        Yv[10] = 2.89061144f * x * y * z;
        Yv[11] = 0.45704579f * y * (5.f * z * z - 1.f);
        Yv[12] = 0.37317633f * z * (5.f * z * z - 3.f);
        Yv[13] = 0.45704579f * x * (5.f * z * z - 1.f);
        Yv[14] = 1.44530572f * z * (x * x - y * y);
        Yv[15] = 0.59004359f * x * (x * x - 3.f * y * y);
    }

    // basis = hidden1 @ bw2 + bb2 : [64,3] -> regs (H1 read from global)
    float breg = 0.f;
    if (tid < 192) {
        const int v = tid / 3, c = tid % 3;
        const float* h1 = wsH1 + ((size_t)b * 64 + v) * 64;
        float acc = bb2[c];
        #pragma unroll 8
        for (int k = 0; k < 64; ++k) acc = fmaf(h1[k], bw2[k * 3 + c], acc);
        breg = acc;
    }
    __syncthreads();   // sH2, sY ready

    if (tid < 192) sBas[tid] = breg;

    // latent = hidden2 @ cw2 + cb2 : [64,64], 4 cols/thread via float4
    for (int t = tid; t < 1024; t += 512) {
        const int row = t >> 4, i4 = (t & 15) * 4;
        const float* h2 = sH2 + row * 129;
        float4 acc = *(const float4*)&cb2[i4];
        #pragma unroll 4
        for (int k = 0; k < 128; ++k) {
            const float  h = h2[k];
            const float4 w = *(const float4*)&cw2[k * 64 + i4];
            acc.x = fmaf(h, w.x, acc.x);
            acc.y = fmaf(h, w.y, acc.y);
            acc.z = fmaf(h, w.z, acc.z);
            acc.w = fmaf(h, w.w, acc.w);
        }
        *(float4*)&sLat[row * 64 + i4] = acc;
    }
    __syncthreads();   // sLat, sBas ready

    // coeffs[m,i] = quad * sum_v Y[v,m] * lat[v,i] ; m in [0,16)
    for (int o = tid; o < 1024; o += 512) {
        const int m = o >> 6, i = o & 63;
        float acc = 0.f;
        #pragma unroll 8
        for (int v = 0; v < 64; ++v) acc = fmaf(sY[v * 16 + m], sLat[v * 64 + i], acc);
        acc *= QUAD;
        sC[o] = acc;
        wsC[(size_t)b * 1024 + o] = acc;
    }
    // E row sums (unnormalized)
    if (tid < 9) {
        const int m = tid / 3, c = tid % 3;
        float acc = 0.f;
        for (int v = 0; v < 64; ++v) acc = fmaf(sY[v * 16 + 1 + m], sBas[v * 3 + c], acc);
        sE[tid] = acc * QUAD;
    }
    __syncthreads();   // sC, sE ready

    if (tid < 9) {
        const int m = tid / 3;
        const float e0 = sE[m * 3 + 0], e1 = sE[m * 3 + 1], e2 = sE[m * 3 + 2];
        const float n = sqrtf(e0 * e0 + e1 * e1 + e2 * e2);
        outE[b * 9 + tid] = sE[tid] / fmaxf(n, 1e-6f);
    }
    // A/B fold of points_inv @ iw
    if (tid < 18) {
        const int which = tid / 9, mc = tid % 9;
        const int m = mc / 3, c = mc % 3;
        float acc = 0.f;
        #pragma unroll 8
        for (int i = 0; i < 64; ++i)
            acc = fmaf(sC[(1 + m) * 64 + i], iw[(2 * i + which) * 3 + c], acc);
        wsAB[b * 18 + tid] = acc;
    }
}

// ============================================================
// Kernel 2: per-point monomials, points_code, coords, grid-sample.
// grid 2048 = 8 batches x 256 groups of 128 points ; 384 threads (6 waves)
//
// phase C thread map, work-balanced (per-thread iter x cost roughly equal):
//   wave 0 (tid   0.. 63): l0, quad q=tid&31, h=tid>>5,   v = 2*vi+h, 64 it
//   wave 1 (tid  64..127): l1, quad q,        h,          v = 2*vi+h, 64 it
//   waves 2-3 (128..255):  l2, quad q=tid&15, s=(t-128)>>4, v = 8*vi+s, 16 it
//   waves 4-5 (256..383):  l3, quad q=tid&15, s=(t-256)>>4, v = 8*vi+s, 16 it
// interleaved v-mapping puts the distinct LDS rows of one wave on disjoint
// bank groups (20-float row stride: rows r..r+3 -> bank offsets 0/20/8/28).
//
// sZ row layout (20 floats, 80B, 16B-aligned rows):
//   f0..f2 = Y1*r (m1..3), f3 = r^2          -> one b128 for l1
//   f4..f10 = Y3*r^3 (m9..15)                -> b128 @f4 + b64 @f8 + b32 @f10
//   f12..f16 = Y2*r^2 (m4..8)                -> b128 @f12 + b32 @f16
// ============================================================
__global__ __launch_bounds__(384) void k_points(
    const float* __restrict__ x, const float* __restrict__ dens,
    const float* __restrict__ ws, const float* __restrict__ ib,
    float* __restrict__ out)
{
    __shared__ alignas(16) float sC[16 * 64];
    __shared__ float sAB[18];
    __shared__ alignas(16) float sZ[128 * 20];

    const int blk = blockIdx.x;       // b*256 + group
    const int b   = blk >> 8;
    const int v0  = (blk & 255) * 128;
    const int tid = threadIdx.x;

    const float* wsC  = ws + WS_C;
    const float* wsAB = ws + WS_AB;

    if (tid < 256) ((float4*)sC)[tid] = ((const float4*)(wsC + (size_t)b * 1024))[tid];
    if (tid < 18) sAB[tid] = wsAB[b * 18 + tid];

    // ---- phase A (pre-barrier): monomials only, waves 0-1 (v = tid) ----
    float z1 = 0.f, z2 = 0.f, z3 = 0.f, r2 = 0.f;
    size_t g = 0;
    if (tid < 128) {
        const int v = v0 + tid;
        g = (size_t)b * 32768 + v;
        const float px = x[g * 3 + 0], py = x[g * 3 + 1], pz = x[g * 3 + 2];
        r2 = px * px + py * py + pz * pz;
        const float r   = sqrtf(r2);
        const float inv = 1.f / fmaxf(r, 1e-6f);
        const float ux = px * inv, uy = py * inv, uz = pz * inv;
        float* Z = sZ + tid * 20;
        z1 = 0.48860251f * uy * r;
        z2 = 0.48860251f * uz * r;
        z3 = 0.48860251f * ux * r;
        Z[0] = z1; Z[1] = z2; Z[2] = z3; Z[3] = r2;
        const float r3 = r2 * r;
        Z[4]  = 0.59004359f * uy * (3.f * ux * ux - uy * uy) * r3;
        Z[5]  = 2.89061144f * ux * uy * uz * r3;
        Z[6]  = 0.45704579f * uy * (5.f * uz * uz - 1.f) * r3;
        Z[7]  = 0.37317633f * uz * (5.f * uz * uz - 3.f) * r3;
        Z[8]  = 0.45704579f * ux * (5.f * uz * uz - 1.f) * r3;
        Z[9]  = 1.44530572f * uz * (ux * ux - uy * uy) * r3;
        Z[10] = 0.59004359f * ux * (ux * ux - 3.f * uy * uy) * r3;
        Z[12] = 1.09254843f * ux * uy * r2;
        Z[13] = 1.09254843f * uy * uz * r2;
        Z[14] = 0.31539157f * (3.f * uz * uz - 1.f) * r2;
        Z[15] = 1.09254843f * ux * uz * r2;
        Z[16] = 0.54627421f * (ux * ux - uy * uy) * r2;
    }
    __syncthreads();

    // ---- phase C ----
    const size_t rowbase = OFF_CODE + ((size_t)b * 32768 + v0) * 384;
    if (tid < 64) {
        // l0: ch 4q..4q+3 = {i=2q,j=0/1, i=2q+1,j=0/1}
        const int q = tid & 31, h = tid >> 5;
        const float ca = sC[2 * q]     * 0.28209479f;
        const float cb = sC[2 * q + 1] * 0.28209479f;
        const float* zr = sZ + h * 20 + 3;
        float* po = out + rowbase + (size_t)h * 384 + 4 * q;
        #pragma unroll 8
        for (int vi = 0; vi < 64; ++vi) {
            const float r2v = zr[vi * 40];
            float4 o; o.x = ca; o.y = ca * r2v; o.z = cb; o.w = cb * r2v;
            *(float4*)po = o;
            po += 768;
        }
    } else if (tid < 128) {
        // l1: ch 128+4q..  two dot3 + r2 variants
        const int u = tid - 64, q = u & 31, h = u >> 5;
        const float c00 = sC[64 + 2 * q],     c01 = sC[128 + 2 * q],     c02 = sC[192 + 2 * q];
        const float c10 = sC[64 + 2 * q + 1], c11 = sC[128 + 2 * q + 1], c12 = sC[192 + 2 * q + 1];
        const float* zr = sZ + h * 20;
        float* po = out + rowbase + (size_t)h * 384 + 128 + 4 * q;
        #pragma unroll 8
        for (int vi = 0; vi < 64; ++vi) {
            const float4 z = *(const float4*)(zr + vi * 40);
            float d0 = c00 * z.x; d0 = fmaf(c01, z.y, d0); d0 = fmaf(c02, z.z, d0);
            float d1 = c10 * z.x; d1 = fmaf(c11, z.y, d1); d1 = fmaf(c12, z.z, d1);
            float4 o; o.x = d0; o.y = d0 * z.w; o.z = d1; o.w = d1 * z.w;
            *(float4*)po = o;
            po += 768;
        }
    } else if (tid < 256) {
        // l2: ch 256+4q..4q+3, dot5 per channel; coeff rows as float4
        const int q = tid & 15, s = (tid - 128) >> 4;
        const int i0 = 4 * q;
        const float4 cf0 = *(const float4*)&sC[4 * 64 + i0];
        const float4 cf1 = *(const float4*)&sC[5 * 64 + i0];
        const float4 cf2 = *(const float4*)&sC[6 * 64 + i0];
        const float4 cf3 = *(const float4*)&sC[7 * 64 + i0];
        const float4 cf4 = *(const float4*)&sC[8 * 64 + i0];
        const float* zr = sZ + s * 20;
        float* po = out + rowbase + (size_t)s * 384 + 256 + i0;
        #pragma unroll 4
        for (int vi = 0; vi < 16; ++vi) {
            const float4 za = *(const float4*)(zr + vi * 160 + 12);
            const float  zb = zr[vi * 160 + 16];
            float a0 = cf0.x * za.x, a1 = cf0.y * za.x, a2 = cf0.z * za.x, a3 = cf0.w * za.x;
            a0 = fmaf(cf1.x, za.y, a0); a1 = fmaf(cf1.y, za.y, a1);
            a2 = fmaf(cf1.z, za.y, a2); a3 = fmaf(cf1.w, za.y, a3);
            a0 = fmaf(cf2.x, za.z, a0); a1 = fmaf(cf2.y, za.z, a1);
            a2 = fmaf(cf2.z, za.z, a2); a3 = fmaf(cf2.w, za.z, a3);
            a0 = fmaf(cf3.x, za.w, a0); a1 = fmaf(cf3.y, za.w, a1);
            a2 = fmaf(cf3.z, za.w, a2); a3 = fmaf(cf3.w, za.w, a3);
            a0 = fmaf(cf4.x, zb, a0);   a1 = fmaf(cf4.y, zb, a1);
            a2 = fmaf(cf4.z, zb, a2);   a3 = fmaf(cf4.w, zb, a3);
            float4 o; o.x = a0; o.y = a1; o.z = a2; o.w = a3;
            *(float4*)po = o;
            po += 3072;                  // 8 rows * 384
        }
    } else {
        // l3: ch 320+4q..4q+3, dot7 per channel
        const int q = tid & 15, s = (tid - 256) >> 4;
        const int i0 = 4 * q;
        const float4 cf0 = *(const float4*)&sC[ 9 * 64 + i0];
        const float4 cf1 = *(const float4*)&sC[10 * 64 + i0];
        const float4 cf2 = *(const float4*)&sC[11 * 64 + i0];
        const float4 cf3 = *(const float4*)&sC[12 * 64 + i0];
        const float4 cf4 = *(const float4*)&sC[13 * 64 + i0];
        const float4 cf5 = *(const float4*)&sC[14 * 64 + i0];
        const float4 cf6 = *(const float4*)&sC[15 * 64 + i0];
        const float* zr = sZ + s * 20;
        float* po = out + rowbase + (size_t)s * 384 + 320 + i0;
        #pragma unroll 4
        for (int vi = 0; vi < 16; ++vi) {
            const float4 za = *(const float4*)(zr + vi * 160 + 4);
            const float2 zb = *(const float2*)(zr + vi * 160 + 8);
            const float  zc = zr[vi * 160 + 10];
            float a0 = cf0.x * za.x, a1 = cf0.y * za.x, a2 = cf0.z * za.x, a3 = cf0.w * za.x;
            a0 = fmaf(cf1.x, za.y, a0); a1 = fmaf(cf1.y, za.y, a1);
            a2 = fmaf(cf1.z, za.y, a2); a3 = fmaf(cf1.w, za.y, a3);
            a0 = fmaf(cf2.x, za.z, a0); a1 = fmaf(cf2.y, za.z, a1);
            a2 = fmaf(cf2.z, za.z, a2); a3 = fmaf(cf2.w, za.z, a3);
            a0 = fmaf(cf3.x, za.w, a0); a1 = fmaf(cf3.y, za.w, a1);
            a2 = fmaf(cf3.z, za.w, a2); a3 = fmaf(cf3.w, za.w, a3);
            a0 = fmaf(cf4.x, zb.x, a0); a1 = fmaf(cf4.y, zb.x, a1);
            a2 = fmaf(cf4.z, zb.x, a2); a3 = fmaf(cf4.w, zb.x, a3);
            a0 = fmaf(cf5.x, zb.y, a0); a1 = fmaf(cf5.y, zb.y, a1);
            a2 = fmaf(cf5.z, zb.y, a2); a3 = fmaf(cf5.w, zb.y, a3);
            a0 = fmaf(cf6.x, zc, a0);   a1 = fmaf(cf6.y, zc, a1);
            a2 = fmaf(cf6.z, zc, a2);   a3 = fmaf(cf6.w, zc, a3);
            float4 o; o.x = a0; o.y = a1; o.z = a2; o.w = a3;
            *(float4*)po = o;
            po += 3072;
        }
    }

    // ---- phase B (post): coords + grid-sample, overlapped with other waves ----
    if (tid < 128) {
        const float zr0 = z1, zr1 = z2, zr2 = z3;
        float pt[3];
        #pragma unroll
        for (int cc = 0; cc < 3; ++cc) {
            float acc = ib[cc];
            acc = fmaf(zr0, sAB[0 * 3 + cc] + r2 * sAB[9 + 0 * 3 + cc], acc);
            acc = fmaf(zr1, sAB[1 * 3 + cc] + r2 * sAB[9 + 1 * 3 + cc], acc);
            acc = fmaf(zr2, sAB[2 * 3 + cc] + r2 * sAB[9 + 2 * 3 + cc], acc);
            pt[cc] = acc;
            out[OFF_COORD + g * 3 + cc] = acc;
        }

        // grid_sample_3d: align_corners=True, zeros padding; vol 32^3
        const float ix = (pt[0] + 1.f) * 0.5f * 31.f;
        const float iy = (pt[1] + 1.f) * 0.5f * 31.f;
        const float iz = (pt[2] + 1.f) * 0.5f * 31.f;
        const float x0f = floorf(ix), y0f = floorf(iy), z0f = floorf(iz);
        const float wx = ix - x0f, wy = iy - y0f, wz = iz - z0f;
        const int x0 = (int)x0f, y0 = (int)y0f, z0 = (int)z0f;
        const float* volb = dens + (size_t)b * 32768;
        float s = 0.f;
        #pragma unroll
        for (int dz = 0; dz < 2; ++dz) {
            const int zi = z0 + dz;
            const float wzz = dz ? wz : 1.f - wz;
            #pragma unroll
            for (int dy = 0; dy < 2; ++dy) {
                const int yi = y0 + dy;
                const float wyy = dy ? wy : 1.f - wy;
                #pragma unroll
                for (int dx = 0; dx < 2; ++dx) {
                    const int xi = x0 + dx;
                    const float wxx = dx ? wx : 1.f - wx;
                    if (zi >= 0 && zi < 32 && yi >= 0 && yi < 32 && xi >= 0 && xi < 32)
                        s += wzz * wyy * wxx * volb[zi * 1024 + yi * 32 + xi];
                }
            }
        }
        out[g] = s;
    }
}

// ============================================================
extern "C" void kernel_launch(void* const* d_in, const int* in_sizes, int n_in,
                              void* d_out, int out_size, void* d_ws, size_t ws_size,
                              hipStream_t stream) {
    const float* x    = (const float*)d_in[0];
    const float* dens = (const float*)d_in[1];
    const float* F    = (const float*)d_in[2];
    const float* S2   = (const float*)d_in[3];
    const float* bw1  = (const float*)d_in[4];
    const float* bb1  = (const float*)d_in[5];
    const float* bw2  = (const float*)d_in[6];
    const float* bb2  = (const float*)d_in[7];
    const float* cw1  = (const float*)d_in[8];
    const float* cb1  = (const float*)d_in[9];
    const float* cw2  = (const float*)d_in[10];
    const float* cb2  = (const float*)d_in[11];
    const float* iw   = (const float*)d_in[12];
    const float* ib   = (const float*)d_in[13];
    float* out = (float*)d_out;
    float* ws  = (float*)d_ws;

    k_hidden<<<64,   384, 0, stream>>>(F, bw1, bb1, cw1, cb1, ws);
    k_coeffs<<<8,    512, 0, stream>>>(ws, S2, bw2, bb2, cw2, cb2, iw, ws, out + OFF_E);
    k_points<<<2048, 384, 0, stream>>>(x, dens, ws, ib, out);
}